// Round 14
// baseline (496.402 us; speedup 1.0000x reference)
//
#include <hip/hip_runtime.h>

#define R_ 4096
#define S_ 64
#define H_ 256
#define N_ (R_ * S_)
#define FARD 1e10f

typedef __attribute__((ext_vector_type(4))) float f32x4;
typedef __attribute__((ext_vector_type(8))) short short8;

union U8 { short8 s; uint4 u; };

__device__ __forceinline__ unsigned int cvt_pk_bf16(float lo, float hi) {
    unsigned int r;
    asm("v_cvt_pk_bf16_f32 %0, %1, %2" : "=v"(r) : "v"(lo), "v"(hi));
    return r;
}
__device__ __forceinline__ unsigned short f2bf(float f) {
    unsigned int x = __float_as_uint(f);
    x += 0x7fffu + ((x >> 16) & 1u);          // RNE
    return (unsigned short)(x >> 16);
}
__device__ __forceinline__ float sigmoidf_(float x) { return 1.0f / (1.0f + expf(-x)); }

// Swizzled byte offset of bf16 act element (m, k); row = 512B. [T2]
__device__ __forceinline__ int act_byte(int m, int k) {
    return ((m << 9) + (k << 1)) ^ ((m & 7) << 4);
}
__device__ __forceinline__ short8 lds_read8(const unsigned short* base, int byte_off) {
    return *(const short8*)((const char*)base + byte_off);
}

// pack 4 fp32 acc -> relu -> 4 bf16 -> one 8B swizzled store
__device__ __forceinline__ void pack_store(unsigned short* act, int m, int n0, f32x4 a) {
    unsigned int u0 = cvt_pk_bf16(fmaxf(a[0], 0.f), fmaxf(a[1], 0.f));
    unsigned int u1 = cvt_pk_bf16(fmaxf(a[2], 0.f), fmaxf(a[3], 0.f));
    *(uint2*)((char*)act + act_byte(m, n0)) = make_uint2(u0, u1);
}

// forced global load: compiler cannot sink/merge these (asm volatile keeps
// program order among themselves; data-dep ties MFMA to the dest regs)
#define GLOAD(dst, ptr) \
    asm volatile("global_load_dwordx4 %0, %1, off" : "=v"(dst) : "v"(ptr))
// counted drain + hard scheduling fence (rule #18: MFMA can be hoisted past an
// asm wait without sched_barrier(0))
#define WAITV(n) do { \
    asm volatile("s_waitcnt vmcnt(" #n ")" ::: "memory"); \
    __builtin_amdgcn_sched_barrier(0); } while (0)

// ---- hidden layer: forced 3-chunk-deep weight prefetch (6 loads in flight,
// counted vmcnt per T4), act from swizzled LDS, one barrier (dbuf ping-pong).
// Regs: ring 32 + acc 32 AGPR + B 16 + addr ~30 -> ~110, inside the 128 bin.
__device__ void hidden_layer(const unsigned short* src, unsigned short* dst,
                             const short* __restrict__ Wt, const float* __restrict__ bias,
                             int lane, int wv)
{
    const int m0 = lane & 15;
    const int q  = lane >> 4;
    const int nw = wv << 5;            // 32 neurons per wave

    f32x4 acc[2][4];                   // 32 AGPR
#pragma unroll
    for (int nt = 0; nt < 2; ++nt) {
        const float4 bv = *(const float4*)&bias[nw + nt * 16 + 4 * q];
#pragma unroll
        for (int mt = 0; mt < 4; ++mt) {
            acc[nt][mt][0] = bv.x; acc[nt][mt][1] = bv.y;
            acc[nt][mt][2] = bv.z; acc[nt][mt][3] = bv.w;
        }
    }

    const short* Abase = Wt + (nw + m0) * H_ + 8 * q;   // per-lane weight base
    short8 Ar[8];                                       // 8-slot prefetch ring

    // prologue: issue loads idx 0..5  (idx = 2*kc + nt; 3 chunks deep)
    GLOAD(Ar[0], Abase + 0 * 32);            GLOAD(Ar[1], Abase + 16 * H_ + 0 * 32);
    GLOAD(Ar[2], Abase + 1 * 32);            GLOAD(Ar[3], Abase + 16 * H_ + 1 * 32);
    GLOAD(Ar[4], Abase + 2 * 32);            GLOAD(Ar[5], Abase + 16 * H_ + 2 * 32);

    __builtin_amdgcn_s_setprio(1);
#define CHUNK(KC, VM) { \
        if (KC < 5) { \
            GLOAD(Ar[(2*KC+6)&7], Abase + (KC+3) * 32); \
            GLOAD(Ar[(2*KC+7)&7], Abase + 16 * H_ + (KC+3) * 32); \
        } \
        short8 B0 = lds_read8(src, act_byte( 0 + m0, KC*32 + 8*q)); \
        short8 B1 = lds_read8(src, act_byte(16 + m0, KC*32 + 8*q)); \
        short8 B2 = lds_read8(src, act_byte(32 + m0, KC*32 + 8*q)); \
        short8 B3 = lds_read8(src, act_byte(48 + m0, KC*32 + 8*q)); \
        WAITV(VM); \
        acc[0][0] = __builtin_amdgcn_mfma_f32_16x16x32_bf16(Ar[(2*KC)&7],   B0, acc[0][0], 0,0,0); \
        acc[0][1] = __builtin_amdgcn_mfma_f32_16x16x32_bf16(Ar[(2*KC)&7],   B1, acc[0][1], 0,0,0); \
        acc[0][2] = __builtin_amdgcn_mfma_f32_16x16x32_bf16(Ar[(2*KC)&7],   B2, acc[0][2], 0,0,0); \
        acc[0][3] = __builtin_amdgcn_mfma_f32_16x16x32_bf16(Ar[(2*KC)&7],   B3, acc[0][3], 0,0,0); \
        acc[1][0] = __builtin_amdgcn_mfma_f32_16x16x32_bf16(Ar[(2*KC+1)&7], B0, acc[1][0], 0,0,0); \
        acc[1][1] = __builtin_amdgcn_mfma_f32_16x16x32_bf16(Ar[(2*KC+1)&7], B1, acc[1][1], 0,0,0); \
        acc[1][2] = __builtin_amdgcn_mfma_f32_16x16x32_bf16(Ar[(2*KC+1)&7], B2, acc[1][2], 0,0,0); \
        acc[1][3] = __builtin_amdgcn_mfma_f32_16x16x32_bf16(Ar[(2*KC+1)&7], B3, acc[1][3], 0,0,0); \
    }
    CHUNK(0, 6); CHUNK(1, 6); CHUNK(2, 6); CHUNK(3, 6);
    CHUNK(4, 6); CHUNK(5, 4); CHUNK(6, 2); CHUNK(7, 0);
#undef CHUNK
    __builtin_amdgcn_s_setprio(0);

#pragma unroll
    for (int nt = 0; nt < 2; ++nt)
#pragma unroll
        for (int mt = 0; mt < 4; ++mt)
            pack_store(dst, mt * 16 + m0, nw + nt * 16 + 4 * q, acc[nt][mt]);
    __syncthreads();   // writes visible; also fences this layer's src reads
}

// ---- input layer via MFMA (K padded to 32; only k=0..7 nonzero, held by q==0 lanes)
__device__ void input_mfma(const float* __restrict__ pts, const float* __restrict__ drs,
                           const float* __restrict__ tv,
                           const short* __restrict__ WinT, const float* __restrict__ bin,
                           unsigned short* dst, int base, int lane, int wv)
{
    const int m0 = lane & 15;
    const int q  = lane >> 4;
    const int nw = wv << 5;

    short8 B[4];
#pragma unroll
    for (int mt = 0; mt < 4; ++mt) {
        U8 ub;
        if (q == 0) {
            const int s = base + mt * 16 + m0;
            float p0 = pts[s * 3 + 0], p1 = pts[s * 3 + 1], p2 = pts[s * 3 + 2];
            float e0 = drs[s * 3 + 0], e1 = drs[s * 3 + 1], e2 = drs[s * 3 + 2];
            float t  = tv[s];
            ub.u = make_uint4(cvt_pk_bf16(p0, p1), cvt_pk_bf16(p2, e0),
                              cvt_pk_bf16(e1, e2), cvt_pk_bf16(t, 0.f));
        } else {
            ub.u = make_uint4(0, 0, 0, 0);
        }
        B[mt] = ub.s;
    }

    f32x4 acc[2][4];
#pragma unroll
    for (int nt = 0; nt < 2; ++nt) {
        const float4 bv = *(const float4*)&bin[nw + nt * 16 + 4 * q];
#pragma unroll
        for (int mt = 0; mt < 4; ++mt) {
            acc[nt][mt][0] = bv.x; acc[nt][mt][1] = bv.y;
            acc[nt][mt][2] = bv.z; acc[nt][mt][3] = bv.w;
        }
    }
#pragma unroll
    for (int nt = 0; nt < 2; ++nt) {
        // rows k>=INK of WinT are zero, so q!=0 slices contribute 0
        short8 A = *(const short8*)&WinT[(nw + nt * 16 + m0) * 32 + 8 * q];
#pragma unroll
        for (int mt = 0; mt < 4; ++mt)
            acc[nt][mt] = __builtin_amdgcn_mfma_f32_16x16x32_bf16(A, B[mt], acc[nt][mt], 0, 0, 0);
    }
#pragma unroll
    for (int nt = 0; nt < 2; ++nt)
#pragma unroll
        for (int mt = 0; mt < 4; ++mt)
            pack_store(dst, mt * 16 + m0, nw + nt * 16 + 4 * q, acc[nt][mt]);
    __syncthreads();
}

// ---- output layer via MFMA: waves 0-3 only; wave owns samples [16wv,16wv+16)
template <int OUTD>
__device__ void out_mfma(const unsigned short* src, const short* __restrict__ WoT,
                         const float* __restrict__ bout, float* obuf, int lane, int wv)
{
    const int m0 = lane & 15;
    const int q  = lane >> 4;
    const int m  = (wv << 4) + m0;

    f32x4 acc = {0.f, 0.f, 0.f, 0.f};
#pragma unroll
    for (int ks = 0; ks < 8; ++ks) {
        short8 A  = *(const short8*)&WoT[m0 * H_ + ks * 32 + 8 * q];
        short8 Bv = lds_read8(src, act_byte(m, ks * 32 + 8 * q));
        acc = __builtin_amdgcn_mfma_f32_16x16x32_bf16(A, Bv, acc, 0, 0, 0);
    }
    if (q == 0) {
        float4 v = make_float4(acc[0] + bout[0], acc[1] + bout[1],
                               acc[2] + bout[2], acc[3] + bout[3]);
        *(float4*)&obuf[m * 8] = v;
    }
    if (OUTD == 5 && q == 1) obuf[m * 8 + 4] = acc[0] + bout[4];
}

// 512 threads = 8 waves x 32 neurons; double-buffered act (68KB LDS, 2 blk/CU).
__global__ __launch_bounds__(512, 4) void nerf_kernel(
    const float* __restrict__ points, const float* __restrict__ dirs,
    const float* __restrict__ z_vals, const float* __restrict__ timev,
    const float* __restrict__ sbin, const float* __restrict__ sbh, const float* __restrict__ sbout,
    const float* __restrict__ dbin, const float* __restrict__ dbh, const float* __restrict__ dbout,
    const short* __restrict__ wsb,
    float* __restrict__ out)
{
    __shared__ unsigned short actA[64 * H_];    // 32KB
    __shared__ unsigned short actB[64 * H_];    // 32KB
    __shared__ float souts[64 * 8];             // 2KB
    __shared__ float douts[64 * 8];             // 2KB

    const int tid  = threadIdx.x;
    const int lane = tid & 63;
    const int wv   = tid >> 6;
    const int ray  = blockIdx.x;
    const int base = ray * 64;

    const short* sWt   = wsb;
    const short* dWt   = wsb + 196608;
    const short* sWinT = wsb + 393216;
    const short* dWinT = wsb + 401408;
    const short* sWoT  = wsb + 409600;
    const short* dWoT  = wsb + 413696;

    // ---- static MLP (ping-pong A->B->A->B) ----
    input_mfma(points, dirs, timev, sWinT, sbin, actA, base, lane, wv);
    hidden_layer(actA, actB, sWt + 0 * 65536, sbh + 0 * H_, lane, wv);
    hidden_layer(actB, actA, sWt + 1 * 65536, sbh + 1 * H_, lane, wv);
    hidden_layer(actA, actB, sWt + 2 * 65536, sbh + 2 * H_, lane, wv);
    if (wv < 4) out_mfma<4>(actB, sWoT, sbout, souts, lane, wv);
    // no barrier: dyn input_mfma's end-barrier orders out's actB reads

    // ---- dynamic MLP ----
    input_mfma(points, dirs, timev, dWinT, dbin, actA, base, lane, wv);
    hidden_layer(actA, actB, dWt + 0 * 65536, dbh + 0 * H_, lane, wv);
    hidden_layer(actB, actA, dWt + 1 * 65536, dbh + 1 * H_, lane, wv);
    hidden_layer(actA, actB, dWt + 2 * 65536, dbh + 2 * H_, lane, wv);
    if (wv < 4) out_mfma<5>(actB, dWoT, dbout, douts, lane, wv);
    __syncthreads();   // souts/douts visible for render

    // ---- mix + fused render: wave 0, lane s = sample
    if (tid < 64) {
        const int s = tid;
        float so0 = souts[s * 8 + 0], so1 = souts[s * 8 + 1];
        float so2 = souts[s * 8 + 2], so3 = souts[s * 8 + 3];
        float d0 = douts[s * 8 + 0], d1 = douts[s * 8 + 1], d2 = douts[s * 8 + 2];
        float d3 = douts[s * 8 + 3], d4 = douts[s * 8 + 4];

        float bw  = sigmoidf_(d4);
        float omb = 1.f - bw;
        float sigma = omb * so0 + bw * d0;
        float cr = omb * sigmoidf_(so1) + bw * sigmoidf_(d1);
        float cg = omb * sigmoidf_(so2) + bw * sigmoidf_(d2);
        float cb = omb * sigmoidf_(so3) + bw * sigmoidf_(d3);

        float z  = z_vals[base + s];
        float zn = __shfl_down(z, 1);
        float delta = (s < 63) ? (zn - z) : FARD;
        float ex    = fminf(-sigma * delta, 60.0f);   // finite where ref overflows
        float alpha = 1.f - expf(ex);
        float f     = 1.f - alpha + 1e-10f;
        float p = f;
#pragma unroll
        for (int d = 1; d < 64; d <<= 1) {
            float pu = __shfl_up(p, d);
            if (s >= d) p *= pu;
        }
        float T = (s == 0) ? 1.f : __shfl_up(p, 1);
        float w = alpha * T;

        float* rgb_map   = out;
        float* depth_map = out + R_ * 3;
        float* weights   = out + R_ * 4;
        float* swei      = weights + N_;
        float* dwei      = swei + N_;
        weights[base + s] = w;
        swei[base + s]    = omb * w;
        dwei[base + s]    = bw * w;

        float c0 = w * cr, c1 = w * cg, c2 = w * cb, dd = w * z;
#pragma unroll
        for (int d = 32; d >= 1; d >>= 1) {
            c0 += __shfl_down(c0, d);
            c1 += __shfl_down(c1, d);
            c2 += __shfl_down(c2, d);
            dd += __shfl_down(dd, d);
        }
        if (s == 0) {
            rgb_map[ray * 3 + 0] = c0;
            rgb_map[ray * 3 + 1] = c1;
            rgb_map[ray * 3 + 2] = c2;
            depth_map[ray] = dd;
        }
    }
}

// ---- prep: all weight transposes/conversions to bf16 into ws
// layout (shorts): sWt[3*65536] dWt[3*65536] sWinT[256*32] dWinT[256*32] sWoT[16*256] dWoT[16*256]
__global__ void convert_weights(const float* __restrict__ sWh, const float* __restrict__ dWh,
                                const float* __restrict__ sWin, const float* __restrict__ dWin,
                                const float* __restrict__ sWout, const float* __restrict__ dWout,
                                short* __restrict__ ws)
{
    int idx = blockIdx.x * 256 + threadIdx.x;      // 417792 total
    float v;
    if (idx < 393216) {
        int which = idx >= 196608;
        int rem   = which ? idx - 196608 : idx;
        int l = rem >> 16, e = rem & 65535, n = e >> 8, k = e & 255;
        const float* W = which ? dWh : sWh;
        v = W[l * 65536 + k * 256 + n];
    } else if (idx < 409600) {
        int j = idx - 393216;
        int which = j >= 8192;
        int e = j & 8191;
        int n = e >> 5, k = e & 31;
        int ink = which ? 7 : 6;
        const float* W = which ? dWin : sWin;
        v = (k < ink) ? W[k * 256 + n] : 0.f;
    } else {
        int j = idx - 409600;
        int which = j >= 4096;
        int e = j & 4095;
        int o = e >> 8, k = e & 255;
        int outd = which ? 5 : 4;
        const float* W = which ? dWout : sWout;
        v = (o < outd) ? W[k * outd + o] : 0.f;
    }
    ws[idx] = (short)f2bf(v);
}

extern "C" void kernel_launch(void* const* d_in, const int* in_sizes, int n_in,
                              void* d_out, int out_size, void* d_ws, size_t ws_size,
                              hipStream_t stream)
{
    const float* points = (const float*)d_in[0];
    const float* dirs   = (const float*)d_in[1];
    const float* z_vals = (const float*)d_in[2];
    const float* timev  = (const float*)d_in[3];
    const float* sWin   = (const float*)d_in[4];
    const float* sbin   = (const float*)d_in[5];
    const float* sWh    = (const float*)d_in[6];
    const float* sbh    = (const float*)d_in[7];
    const float* sWout  = (const float*)d_in[8];
    const float* sbout  = (const float*)d_in[9];
    const float* dWin   = (const float*)d_in[10];
    const float* dbin   = (const float*)d_in[11];
    const float* dWh    = (const float*)d_in[12];
    const float* dbh    = (const float*)d_in[13];
    const float* dWout  = (const float*)d_in[14];
    const float* dbout  = (const float*)d_in[15];

    short* wsb = (short*)d_ws;

    convert_weights<<<1632, 256, 0, stream>>>(sWh, dWh, sWin, dWin, sWout, dWout, wsb);

    nerf_kernel<<<R_, 512, 0, stream>>>(
        points, dirs, z_vals, timev,
        sbin, sbh, sbout, dbin, dbh, dbout,
        wsb, (float*)d_out);
}

// Round 15
// 436.836 us; speedup vs baseline: 1.1364x; 1.1364x over previous
//
#include <hip/hip_runtime.h>

#define R_ 4096
#define S_ 64
#define H_ 256
#define N_ (R_ * S_)
#define FARD 1e10f

typedef __attribute__((ext_vector_type(4))) float f32x4;
typedef __attribute__((ext_vector_type(8))) short short8;

union U8 { short8 s; uint4 u; };

__device__ __forceinline__ unsigned int cvt_pk_bf16(float lo, float hi) {
    unsigned int r;
    asm("v_cvt_pk_bf16_f32 %0, %1, %2" : "=v"(r) : "v"(lo), "v"(hi));
    return r;
}
__device__ __forceinline__ unsigned short f2bf(float f) {
    unsigned int x = __float_as_uint(f);
    x += 0x7fffu + ((x >> 16) & 1u);          // RNE
    return (unsigned short)(x >> 16);
}
// pack 4 f32 -> 4 fp8 e4m3 (OCP) in one u32
__device__ __forceinline__ unsigned int pk4_fp8(float a0, float a1, float a2, float a3) {
    unsigned int lo, hi;
    asm("v_cvt_pk_fp8_f32 %0, %1, %2" : "=v"(lo) : "v"(a0), "v"(a1));
    asm("v_cvt_pk_fp8_f32 %0, %1, %2" : "=v"(hi) : "v"(a2), "v"(a3));
    return (lo & 0xffffu) | (hi << 16);
}
__device__ __forceinline__ unsigned char f2fp8(float v) {
    unsigned int r;
    asm("v_cvt_pk_fp8_f32 %0, %1, %2" : "=v"(r) : "v"(v), "v"(0.0f));
    return (unsigned char)(r & 0xff);
}
__device__ __forceinline__ float sigmoidf_(float x) { return 1.0f / (1.0f + expf(-x)); }

// fp8 act layout: row m = 256B. Swizzle XOR bits 5-7 with m&7 -> per-b64-read
// each bank-pair gets exactly 4 lanes (4 sweeps, balanced) = conflict-free.
__device__ __forceinline__ int fp8_byte(int m, int k) {
    return ((m << 8) + k) ^ ((m & 7) << 5);
}

// relu + pack 4 fp8 -> one 4B swizzled store
__device__ __forceinline__ void store_fp8(unsigned char* act, int m, int n0, f32x4 a) {
    unsigned int u = pk4_fp8(fmaxf(a[0], 0.f), fmaxf(a[1], 0.f),
                             fmaxf(a[2], 0.f), fmaxf(a[3], 0.f));
    *(unsigned int*)(act + fp8_byte(m, n0)) = u;
}

// ---- hidden layer fp8: dbuf ping-pong, one barrier. 8 waves x 32 neurons.
// acc 32 AGPR + A/B fp8 operands (2 VGPR each) -> low pressure, 4 waves/SIMD.
__device__ void hidden_layer(const unsigned char* src, unsigned char* dst,
                             const unsigned char* __restrict__ Wt,
                             const float* __restrict__ bias, int lane, int wv)
{
    const int m0 = lane & 15;
    const int q  = lane >> 4;
    const int nw = wv << 5;            // 32 neurons per wave

    f32x4 acc[2][4];
#pragma unroll
    for (int nt = 0; nt < 2; ++nt) {
        const float4 bv = *(const float4*)&bias[nw + nt * 16 + 4 * q];
#pragma unroll
        for (int mt = 0; mt < 4; ++mt) {
            acc[nt][mt][0] = bv.x; acc[nt][mt][1] = bv.y;
            acc[nt][mt][2] = bv.z; acc[nt][mt][3] = bv.w;
        }
    }

    const unsigned char* Ab = Wt + (nw + m0) * H_ + 8 * q;
    __builtin_amdgcn_s_setprio(1);
#pragma unroll
    for (int kc = 0; kc < 8; ++kc) {               // K = 8 chunks of 32
        const int kb = kc * 32;
        long long B[4];
#pragma unroll
        for (int mt = 0; mt < 4; ++mt)
            B[mt] = *(const long long*)(src + fp8_byte(mt * 16 + m0, kb + 8 * q));
#pragma unroll
        for (int nt = 0; nt < 2; ++nt) {
            long long A = *(const long long*)(Ab + nt * 16 * H_ + kb);
#pragma unroll
            for (int mt = 0; mt < 4; ++mt)
                acc[nt][mt] = __builtin_amdgcn_mfma_f32_16x16x32_fp8_fp8(
                    A, B[mt], acc[nt][mt], 0, 0, 0);
        }
    }
    __builtin_amdgcn_s_setprio(0);
#pragma unroll
    for (int nt = 0; nt < 2; ++nt)
#pragma unroll
        for (int mt = 0; mt < 4; ++mt)
            store_fp8(dst, mt * 16 + m0, nw + nt * 16 + 4 * q, acc[nt][mt]);
    __syncthreads();   // writes visible; also fences this layer's src reads
}

// ---- input layer: bf16 MFMA (keeps input precision), fp8 act output
__device__ void input_mfma(const float* __restrict__ pts, const float* __restrict__ drs,
                           const float* __restrict__ tv,
                           const short* __restrict__ WinT, const float* __restrict__ bin,
                           unsigned char* dst, int base, int lane, int wv)
{
    const int m0 = lane & 15;
    const int q  = lane >> 4;
    const int nw = wv << 5;

    short8 B[4];
#pragma unroll
    for (int mt = 0; mt < 4; ++mt) {
        U8 ub;
        if (q == 0) {
            const int s = base + mt * 16 + m0;
            float p0 = pts[s * 3 + 0], p1 = pts[s * 3 + 1], p2 = pts[s * 3 + 2];
            float e0 = drs[s * 3 + 0], e1 = drs[s * 3 + 1], e2 = drs[s * 3 + 2];
            float t  = tv[s];
            ub.u = make_uint4(cvt_pk_bf16(p0, p1), cvt_pk_bf16(p2, e0),
                              cvt_pk_bf16(e1, e2), cvt_pk_bf16(t, 0.f));
        } else {
            ub.u = make_uint4(0, 0, 0, 0);
        }
        B[mt] = ub.s;
    }

    f32x4 acc[2][4];
#pragma unroll
    for (int nt = 0; nt < 2; ++nt) {
        const float4 bv = *(const float4*)&bin[nw + nt * 16 + 4 * q];
#pragma unroll
        for (int mt = 0; mt < 4; ++mt) {
            acc[nt][mt][0] = bv.x; acc[nt][mt][1] = bv.y;
            acc[nt][mt][2] = bv.z; acc[nt][mt][3] = bv.w;
        }
    }
#pragma unroll
    for (int nt = 0; nt < 2; ++nt) {
        // rows k>=INK of WinT are zero, so q!=0 slices contribute 0
        short8 A = *(const short8*)&WinT[(nw + nt * 16 + m0) * 32 + 8 * q];
#pragma unroll
        for (int mt = 0; mt < 4; ++mt)
            acc[nt][mt] = __builtin_amdgcn_mfma_f32_16x16x32_bf16(A, B[mt], acc[nt][mt], 0, 0, 0);
    }
#pragma unroll
    for (int nt = 0; nt < 2; ++nt)
#pragma unroll
        for (int mt = 0; mt < 4; ++mt)
            store_fp8(dst, mt * 16 + m0, nw + nt * 16 + 4 * q, acc[nt][mt]);
    __syncthreads();
}

// ---- output layer fp8: waves 0-3; wave owns samples [16wv,16wv+16)
template <int OUTD>
__device__ void out_mfma(const unsigned char* src, const unsigned char* __restrict__ WoT,
                         const float* __restrict__ bout, float* obuf, int lane, int wv)
{
    const int m0 = lane & 15;
    const int q  = lane >> 4;
    const int m  = (wv << 4) + m0;

    f32x4 acc = {0.f, 0.f, 0.f, 0.f};
#pragma unroll
    for (int ks = 0; ks < 8; ++ks) {
        long long A = *(const long long*)(WoT + m0 * H_ + ks * 32 + 8 * q);
        long long B = *(const long long*)(src + fp8_byte(m, ks * 32 + 8 * q));
        acc = __builtin_amdgcn_mfma_f32_16x16x32_fp8_fp8(A, B, acc, 0, 0, 0);
    }
    if (q == 0) {
        float4 v = make_float4(acc[0] + bout[0], acc[1] + bout[1],
                               acc[2] + bout[2], acc[3] + bout[3]);
        *(float4*)&obuf[m * 8] = v;
    }
    if (OUTD == 5 && q == 1) obuf[m * 8 + 4] = acc[0] + bout[4];
}

// 512 threads = 8 waves x 32 neurons; fp8 dbuf act = 2 x 16KB LDS.
__global__ __launch_bounds__(512, 4) void nerf_kernel(
    const float* __restrict__ points, const float* __restrict__ dirs,
    const float* __restrict__ z_vals, const float* __restrict__ timev,
    const float* __restrict__ sbin, const float* __restrict__ sbh, const float* __restrict__ sbout,
    const float* __restrict__ dbin, const float* __restrict__ dbh, const float* __restrict__ dbout,
    const unsigned char* __restrict__ wsb,
    float* __restrict__ out)
{
    __shared__ __align__(16) unsigned char actA[64 * H_];   // 16KB
    __shared__ __align__(16) unsigned char actB[64 * H_];   // 16KB
    __shared__ float souts[64 * 8];                         // 2KB
    __shared__ float douts[64 * 8];                         // 2KB

    const int tid  = threadIdx.x;
    const int lane = tid & 63;
    const int wv   = tid >> 6;
    const int ray  = blockIdx.x;
    const int base = ray * 64;

    const unsigned char* sWt8  = wsb;                    // 3*65536 fp8
    const unsigned char* dWt8  = wsb + 196608;
    const short* sWinT = (const short*)(wsb + 393216);   // 256*32 bf16
    const short* dWinT = (const short*)(wsb + 409600);
    const unsigned char* sWoT8 = wsb + 425984;           // 16*256 fp8
    const unsigned char* dWoT8 = wsb + 430080;

    // ---- static MLP (ping-pong A->B->A->B) ----
    input_mfma(points, dirs, timev, sWinT, sbin, actA, base, lane, wv);
    hidden_layer(actA, actB, sWt8 + 0 * 65536, sbh + 0 * H_, lane, wv);
    hidden_layer(actB, actA, sWt8 + 1 * 65536, sbh + 1 * H_, lane, wv);
    hidden_layer(actA, actB, sWt8 + 2 * 65536, sbh + 2 * H_, lane, wv);
    if (wv < 4) out_mfma<4>(actB, sWoT8, sbout, souts, lane, wv);
    // no barrier: dyn input_mfma's end-barrier orders out's actB reads

    // ---- dynamic MLP ----
    input_mfma(points, dirs, timev, dWinT, dbin, actA, base, lane, wv);
    hidden_layer(actA, actB, dWt8 + 0 * 65536, dbh + 0 * H_, lane, wv);
    hidden_layer(actB, actA, dWt8 + 1 * 65536, dbh + 1 * H_, lane, wv);
    hidden_layer(actA, actB, dWt8 + 2 * 65536, dbh + 2 * H_, lane, wv);
    if (wv < 4) out_mfma<5>(actB, dWoT8, dbout, douts, lane, wv);
    __syncthreads();   // souts/douts visible for render

    // ---- mix + fused render: wave 0, lane s = sample
    if (tid < 64) {
        const int s = tid;
        float so0 = souts[s * 8 + 0], so1 = souts[s * 8 + 1];
        float so2 = souts[s * 8 + 2], so3 = souts[s * 8 + 3];
        float d0 = douts[s * 8 + 0], d1 = douts[s * 8 + 1], d2 = douts[s * 8 + 2];
        float d3 = douts[s * 8 + 3], d4 = douts[s * 8 + 4];

        float bw  = sigmoidf_(d4);
        float omb = 1.f - bw;
        float sigma = omb * so0 + bw * d0;
        float cr = omb * sigmoidf_(so1) + bw * sigmoidf_(d1);
        float cg = omb * sigmoidf_(so2) + bw * sigmoidf_(d2);
        float cb = omb * sigmoidf_(so3) + bw * sigmoidf_(d3);

        float z  = z_vals[base + s];
        float zn = __shfl_down(z, 1);
        float delta = (s < 63) ? (zn - z) : FARD;
        float ex    = fminf(-sigma * delta, 60.0f);   // finite where ref overflows
        float alpha = 1.f - expf(ex);
        float f     = 1.f - alpha + 1e-10f;
        float p = f;
#pragma unroll
        for (int d = 1; d < 64; d <<= 1) {
            float pu = __shfl_up(p, d);
            if (s >= d) p *= pu;
        }
        float T = (s == 0) ? 1.f : __shfl_up(p, 1);
        float w = alpha * T;

        float* rgb_map   = out;
        float* depth_map = out + R_ * 3;
        float* weights   = out + R_ * 4;
        float* swei      = weights + N_;
        float* dwei      = swei + N_;
        weights[base + s] = w;
        swei[base + s]    = omb * w;
        dwei[base + s]    = bw * w;

        float c0 = w * cr, c1 = w * cg, c2 = w * cb, dd = w * z;
#pragma unroll
        for (int d = 32; d >= 1; d >>= 1) {
            c0 += __shfl_down(c0, d);
            c1 += __shfl_down(c1, d);
            c2 += __shfl_down(c2, d);
            dd += __shfl_down(dd, d);
        }
        if (s == 0) {
            rgb_map[ray * 3 + 0] = c0;
            rgb_map[ray * 3 + 1] = c1;
            rgb_map[ray * 3 + 2] = c2;
            depth_map[ray] = dd;
        }
    }
}

// ---- prep: weight transpose + convert. Layout (bytes):
// [0)        sWt8   3*65536 fp8  [l][n][k]
// [196608)   dWt8   3*65536 fp8
// [393216)   sWinT  256*32 bf16 (k>=6 zero-padded)
// [409600)   dWinT  256*32 bf16 (k>=7 zero-padded)
// [425984)   sWoT8  16*256 fp8  (o>=4 zero-padded)
// [430080)   dWoT8  16*256 fp8  (o>=5 zero-padded)
__global__ void convert_weights(const float* __restrict__ sWh, const float* __restrict__ dWh,
                                const float* __restrict__ sWin, const float* __restrict__ dWin,
                                const float* __restrict__ sWout, const float* __restrict__ dWout,
                                unsigned char* __restrict__ ws)
{
    int idx = blockIdx.x * 256 + threadIdx.x;      // 417792 total
    if (idx < 393216) {
        int which = idx >= 196608;
        int rem   = which ? idx - 196608 : idx;
        int l = rem >> 16, e = rem & 65535, n = e >> 8, k = e & 255;
        const float* W = which ? dWh : sWh;
        ws[idx] = f2fp8(W[l * 65536 + k * 256 + n]);
    } else if (idx < 409600) {
        int j = idx - 393216;                      // [0, 16384)
        int which = j >= 8192;
        int e = j & 8191;
        int n = e >> 5, k = e & 31;
        int ink = which ? 7 : 6;
        const float* W = which ? dWin : sWin;
        float v = (k < ink) ? W[k * 256 + n] : 0.f;
        ((short*)(ws + 393216))[j] = (short)f2bf(v);
    } else {
        int j = idx - 409600;                      // [0, 8192)
        int which = j >= 4096;
        int e = j & 4095;
        int o = e >> 8, k = e & 255;
        int outd = which ? 5 : 4;
        const float* W = which ? dWout : sWout;
        float v = (o < outd) ? W[k * outd + o] : 0.f;
        ws[425984 + j] = f2fp8(v);
    }
}

extern "C" void kernel_launch(void* const* d_in, const int* in_sizes, int n_in,
                              void* d_out, int out_size, void* d_ws, size_t ws_size,
                              hipStream_t stream)
{
    const float* points = (const float*)d_in[0];
    const float* dirs   = (const float*)d_in[1];
    const float* z_vals = (const float*)d_in[2];
    const float* timev  = (const float*)d_in[3];
    const float* sWin   = (const float*)d_in[4];
    const float* sbin   = (const float*)d_in[5];
    const float* sWh    = (const float*)d_in[6];
    const float* sbh    = (const float*)d_in[7];
    const float* sWout  = (const float*)d_in[8];
    const float* sbout  = (const float*)d_in[9];
    const float* dWin   = (const float*)d_in[10];
    const float* dbin   = (const float*)d_in[11];
    const float* dWh    = (const float*)d_in[12];
    const float* dbh    = (const float*)d_in[13];
    const float* dWout  = (const float*)d_in[14];
    const float* dbout  = (const float*)d_in[15];

    unsigned char* wsb = (unsigned char*)d_ws;

    convert_weights<<<1632, 256, 0, stream>>>(sWh, dWh, sWin, dWin, sWout, dWout, wsb);

    nerf_kernel<<<R_, 512, 0, stream>>>(
        points, dirs, z_vals, timev,
        sbin, sbh, sbout, dbin, dbh, dbout,
        wsb, (float*)d_out);
}

// Round 16
// 308.587 us; speedup vs baseline: 1.6086x; 1.4156x over previous
//
#include <hip/hip_runtime.h>

#define R_ 4096
#define S_ 64
#define H_ 256
#define N_ (R_ * S_)
#define FARD 1e10f

typedef __attribute__((ext_vector_type(4))) float f32x4;
typedef __attribute__((ext_vector_type(8))) short short8;

union U8 { short8 s; uint4 u; };

__device__ __forceinline__ unsigned int cvt_pk_bf16(float lo, float hi) {
    unsigned int r;
    asm("v_cvt_pk_bf16_f32 %0, %1, %2" : "=v"(r) : "v"(lo), "v"(hi));
    return r;
}
__device__ __forceinline__ unsigned short f2bf(float f) {
    unsigned int x = __float_as_uint(f);
    x += 0x7fffu + ((x >> 16) & 1u);          // RNE
    return (unsigned short)(x >> 16);
}
__device__ __forceinline__ unsigned int pk4_fp8(float a0, float a1, float a2, float a3) {
    unsigned int lo, hi;
    asm("v_cvt_pk_fp8_f32 %0, %1, %2" : "=v"(lo) : "v"(a0), "v"(a1));
    asm("v_cvt_pk_fp8_f32 %0, %1, %2" : "=v"(hi) : "v"(a2), "v"(a3));
    return (lo & 0xffffu) | (hi << 16);
}
__device__ __forceinline__ unsigned char f2fp8(float v) {
    unsigned int r;
    asm("v_cvt_pk_fp8_f32 %0, %1, %2" : "=v"(r) : "v"(v), "v"(0.0f));
    return (unsigned char)(r & 0xff);
}
__device__ __forceinline__ float sigmoidf_(float x) { return 1.0f / (1.0f + expf(-x)); }

// Swizzled byte offset in a [row][256] fp8 panel: XOR col bits 3-6 with row&15.
// A 16-lane column-slice b64 read (same col, rows r..r+15) then covers 16
// distinct 8B slots = all 32 banks -> conflict-free (verified bitwise).
__device__ __forceinline__ int sw_byte(int row, int col) {
    return (row << 8) + (col ^ ((row & 15) << 3));
}

typedef const __attribute__((address_space(1))) unsigned char* gas1;
typedef __attribute__((address_space(3))) unsigned char* las3;
// async DMA 64KB global->LDS (8 x 512 threads x 16B), no VGPR round-trip.
// LDS dest is wave-uniform base + lane*16 (m104) -> tid*16 linear layout works;
// swizzle is pre-baked into the GLOBAL layout by convert_weights (m173 pattern).
__device__ __forceinline__ void stage64k(const unsigned char* g, unsigned char* l, int tid) {
#pragma unroll
    for (int i = 0; i < 8; ++i)
        __builtin_amdgcn_global_load_lds((gas1)(g + i * 8192 + tid * 16),
                                         (las3)(l + i * 8192 + tid * 16), 16, 0, 0);
}

// ---- hidden layer: act AND weights from LDS (both swizzled fp8), in-place act.
// compute -> sync -> store; caller's next sync publishes writes + drains staging.
__device__ void hidden_layer(unsigned char* act, const unsigned char* wlds,
                             const float* __restrict__ bias, int lane, int wv)
{
    const int m0 = lane & 15;
    const int q  = lane >> 4;
    const int nw = wv << 5;            // 32 neurons per wave

    f32x4 acc[2][4];                   // 32 AGPR
#pragma unroll
    for (int nt = 0; nt < 2; ++nt) {
        const float4 bv = *(const float4*)&bias[nw + nt * 16 + 4 * q];
#pragma unroll
        for (int mt = 0; mt < 4; ++mt) {
            acc[nt][mt][0] = bv.x; acc[nt][mt][1] = bv.y;
            acc[nt][mt][2] = bv.z; acc[nt][mt][3] = bv.w;
        }
    }

    __builtin_amdgcn_s_setprio(1);
#pragma unroll
    for (int kc = 0; kc < 8; ++kc) {               // K = 8 chunks of 32
        const int kb = kc * 32 + 8 * q;
        long long B[4];
#pragma unroll
        for (int mt = 0; mt < 4; ++mt)
            B[mt] = *(const long long*)(act + sw_byte(mt * 16 + m0, kb));
#pragma unroll
        for (int nt = 0; nt < 2; ++nt) {
            long long A = *(const long long*)(wlds + sw_byte(nw + nt * 16 + m0, kb));
#pragma unroll
            for (int mt = 0; mt < 4; ++mt)
                acc[nt][mt] = __builtin_amdgcn_mfma_f32_16x16x32_fp8_fp8(
                    A, B[mt], acc[nt][mt], 0, 0, 0);
        }
    }
    __builtin_amdgcn_s_setprio(0);
    __syncthreads();   // all act reads complete (in-place hazard)
#pragma unroll
    for (int nt = 0; nt < 2; ++nt)
#pragma unroll
        for (int mt = 0; mt < 4; ++mt) {
            f32x4 a = acc[nt][mt];
            unsigned int u = pk4_fp8(fmaxf(a[0], 0.f), fmaxf(a[1], 0.f),
                                     fmaxf(a[2], 0.f), fmaxf(a[3], 0.f));
            *(unsigned int*)(act + sw_byte(mt * 16 + m0, nw + nt * 16 + 4 * q)) = u;
        }
}

// ---- input layer: bf16 MFMA, fp8 swizzled act output. NO trailing sync.
__device__ void input_mfma(const float* __restrict__ pts, const float* __restrict__ drs,
                           const float* __restrict__ tv,
                           const short* __restrict__ WinT, const float* __restrict__ bin,
                           unsigned char* act, int base, int lane, int wv)
{
    const int m0 = lane & 15;
    const int q  = lane >> 4;
    const int nw = wv << 5;

    short8 B[4];
#pragma unroll
    for (int mt = 0; mt < 4; ++mt) {
        U8 ub;
        if (q == 0) {
            const int s = base + mt * 16 + m0;
            float p0 = pts[s * 3 + 0], p1 = pts[s * 3 + 1], p2 = pts[s * 3 + 2];
            float e0 = drs[s * 3 + 0], e1 = drs[s * 3 + 1], e2 = drs[s * 3 + 2];
            float t  = tv[s];
            ub.u = make_uint4(cvt_pk_bf16(p0, p1), cvt_pk_bf16(p2, e0),
                              cvt_pk_bf16(e1, e2), cvt_pk_bf16(t, 0.f));
        } else {
            ub.u = make_uint4(0, 0, 0, 0);
        }
        B[mt] = ub.s;
    }

    f32x4 acc[2][4];
#pragma unroll
    for (int nt = 0; nt < 2; ++nt) {
        const float4 bv = *(const float4*)&bin[nw + nt * 16 + 4 * q];
#pragma unroll
        for (int mt = 0; mt < 4; ++mt) {
            acc[nt][mt][0] = bv.x; acc[nt][mt][1] = bv.y;
            acc[nt][mt][2] = bv.z; acc[nt][mt][3] = bv.w;
        }
    }
#pragma unroll
    for (int nt = 0; nt < 2; ++nt) {
        // rows k>=INK of WinT are zero, so q!=0 slices contribute 0
        short8 A = *(const short8*)&WinT[(nw + nt * 16 + m0) * 32 + 8 * q];
#pragma unroll
        for (int mt = 0; mt < 4; ++mt)
            acc[nt][mt] = __builtin_amdgcn_mfma_f32_16x16x32_bf16(A, B[mt], acc[nt][mt], 0, 0, 0);
    }
#pragma unroll
    for (int nt = 0; nt < 2; ++nt)
#pragma unroll
        for (int mt = 0; mt < 4; ++mt) {
            f32x4 a = acc[nt][mt];
            unsigned int u = pk4_fp8(fmaxf(a[0], 0.f), fmaxf(a[1], 0.f),
                                     fmaxf(a[2], 0.f), fmaxf(a[3], 0.f));
            *(unsigned int*)(act + sw_byte(mt * 16 + m0, nw + nt * 16 + 4 * q)) = u;
        }
}

// ---- output layer fp8: waves 0-3; wave owns samples [16wv,16wv+16)
template <int OUTD>
__device__ void out_mfma(const unsigned char* act, const unsigned char* __restrict__ WoT,
                         const float* __restrict__ bout, float* obuf, int lane, int wv)
{
    const int m0 = lane & 15;
    const int q  = lane >> 4;
    const int m  = (wv << 4) + m0;

    f32x4 acc = {0.f, 0.f, 0.f, 0.f};
#pragma unroll
    for (int ks = 0; ks < 8; ++ks) {
        long long A = *(const long long*)(WoT + m0 * H_ + ks * 32 + 8 * q);
        long long B = *(const long long*)(act + sw_byte(m, ks * 32 + 8 * q));
        acc = __builtin_amdgcn_mfma_f32_16x16x32_fp8_fp8(A, B, acc, 0, 0, 0);
    }
    if (q == 0) {
        float4 v = make_float4(acc[0] + bout[0], acc[1] + bout[1],
                               acc[2] + bout[2], acc[3] + bout[3]);
        *(float4*)&obuf[m * 8] = v;
    }
    if (OUTD == 5 && q == 1) obuf[m * 8 + 4] = acc[0] + bout[4];
}

// 512 threads = 8 waves x 32 neurons. LDS: 2x64K weight dbuf + 16K act + 4K
// = 148KB -> 1 block/CU. Weights staged by async DMA one layer ahead.
__global__ __launch_bounds__(512) void nerf_kernel(
    const float* __restrict__ points, const float* __restrict__ dirs,
    const float* __restrict__ z_vals, const float* __restrict__ timev,
    const float* __restrict__ sbin, const float* __restrict__ sbh, const float* __restrict__ sbout,
    const float* __restrict__ dbin, const float* __restrict__ dbh, const float* __restrict__ dbout,
    const unsigned char* __restrict__ wsb,
    float* __restrict__ out)
{
    __shared__ __align__(16) unsigned char wbuf0[65536];
    __shared__ __align__(16) unsigned char wbuf1[65536];
    __shared__ __align__(16) unsigned char act[64 * H_];   // 16KB, in-place
    __shared__ float souts[64 * 8];
    __shared__ float douts[64 * 8];

    const int tid  = threadIdx.x;
    const int lane = tid & 63;
    const int wv   = tid >> 6;
    const int ray  = blockIdx.x;
    const int base = ray * 64;

    const unsigned char* sW8   = wsb;                    // 3*65536 fp8, pre-swizzled
    const unsigned char* dW8   = wsb + 196608;
    const short* sWinT = (const short*)(wsb + 393216);   // 256*32 bf16
    const short* dWinT = (const short*)(wsb + 409600);
    const unsigned char* sWoT8 = wsb + 425984;           // 16*256 fp8
    const unsigned char* dWoT8 = wsb + 430080;

    // ---- static MLP ----
    stage64k(sW8 + 0 * 65536, wbuf0, tid);               // s_h0 -> w0
    input_mfma(points, dirs, timev, sWinT, sbin, act, base, lane, wv);
    __syncthreads();                                     // act ready + w0 staged (vmcnt drained)
    stage64k(sW8 + 1 * 65536, wbuf1, tid);               // s_h1 -> w1 (overlaps h0 compute)
    hidden_layer(act, wbuf0, sbh + 0 * H_, lane, wv);
    __syncthreads();
    stage64k(sW8 + 2 * 65536, wbuf0, tid);               // s_h2 -> w0
    hidden_layer(act, wbuf1, sbh + 1 * H_, lane, wv);
    __syncthreads();
    stage64k(dW8 + 0 * 65536, wbuf1, tid);               // d_h0 -> w1
    hidden_layer(act, wbuf0, sbh + 2 * H_, lane, wv);
    __syncthreads();                                     // final static act ready
    if (wv < 4) out_mfma<4>(act, sWoT8, sbout, souts, lane, wv);
    __syncthreads();                                     // out reads done before overwrite

    // ---- dynamic MLP ----
    input_mfma(points, dirs, timev, dWinT, dbin, act, base, lane, wv);
    __syncthreads();                                     // act ready (d_h0 long staged)
    stage64k(dW8 + 1 * 65536, wbuf0, tid);               // d_h1 -> w0
    hidden_layer(act, wbuf1, dbh + 0 * H_, lane, wv);
    __syncthreads();
    stage64k(dW8 + 2 * 65536, wbuf1, tid);               // d_h2 -> w1
    hidden_layer(act, wbuf0, dbh + 1 * H_, lane, wv);
    __syncthreads();
    hidden_layer(act, wbuf1, dbh + 2 * H_, lane, wv);
    __syncthreads();
    if (wv < 4) out_mfma<5>(act, dWoT8, dbout, douts, lane, wv);
    __syncthreads();

    // ---- mix + fused render: wave 0, lane s = sample
    if (tid < 64) {
        const int s = tid;
        float so0 = souts[s * 8 + 0], so1 = souts[s * 8 + 1];
        float so2 = souts[s * 8 + 2], so3 = souts[s * 8 + 3];
        float d0 = douts[s * 8 + 0], d1 = douts[s * 8 + 1], d2 = douts[s * 8 + 2];
        float d3 = douts[s * 8 + 3], d4 = douts[s * 8 + 4];

        float bw  = sigmoidf_(d4);
        float omb = 1.f - bw;
        float sigma = omb * so0 + bw * d0;
        float cr = omb * sigmoidf_(so1) + bw * sigmoidf_(d1);
        float cg = omb * sigmoidf_(so2) + bw * sigmoidf_(d2);
        float cb = omb * sigmoidf_(so3) + bw * sigmoidf_(d3);

        float z  = z_vals[base + s];
        float zn = __shfl_down(z, 1);
        float delta = (s < 63) ? (zn - z) : FARD;
        float ex    = fminf(-sigma * delta, 60.0f);   // finite where ref overflows
        float alpha = 1.f - expf(ex);
        float f     = 1.f - alpha + 1e-10f;
        float p = f;
#pragma unroll
        for (int d = 1; d < 64; d <<= 1) {
            float pu = __shfl_up(p, d);
            if (s >= d) p *= pu;
        }
        float T = (s == 0) ? 1.f : __shfl_up(p, 1);
        float w = alpha * T;

        float* rgb_map   = out;
        float* depth_map = out + R_ * 3;
        float* weights   = out + R_ * 4;
        float* swei      = weights + N_;
        float* dwei      = swei + N_;
        weights[base + s] = w;
        swei[base + s]    = omb * w;
        dwei[base + s]    = bw * w;

        float c0 = w * cr, c1 = w * cg, c2 = w * cb, dd = w * z;
#pragma unroll
        for (int d = 32; d >= 1; d >>= 1) {
            c0 += __shfl_down(c0, d);
            c1 += __shfl_down(c1, d);
            c2 += __shfl_down(c2, d);
            dd += __shfl_down(dd, d);
        }
        if (s == 0) {
            rgb_map[ray * 3 + 0] = c0;
            rgb_map[ray * 3 + 1] = c1;
            rgb_map[ray * 3 + 2] = c2;
            depth_map[ray] = dd;
        }
    }
}

// ---- prep. Layout (bytes):
// [0)        sW8    3*65536 fp8  PRE-SWIZZLED [l][n][k^((n&15)<<3)] = W[l][k][n]
// [196608)   dW8    3*65536 fp8  same
// [393216)   sWinT  256*32 bf16 (k>=6 zero-padded)
// [409600)   dWinT  256*32 bf16 (k>=7 zero-padded)
// [425984)   sWoT8  16*256 fp8  (o>=4 zero-padded)
// [430080)   dWoT8  16*256 fp8  (o>=5 zero-padded)
__global__ void convert_weights(const float* __restrict__ sWh, const float* __restrict__ dWh,
                                const float* __restrict__ sWin, const float* __restrict__ dWin,
                                const float* __restrict__ sWout, const float* __restrict__ dWout,
                                unsigned char* __restrict__ ws)
{
    int idx = blockIdx.x * 256 + threadIdx.x;      // 417792 total
    if (idx < 393216) {
        int which = idx >= 196608;
        int rem   = which ? idx - 196608 : idx;
        int l = rem >> 16, e = rem & 65535, k = e >> 8, n = e & 255;
        const float* W = which ? dWh : sWh;
        int dst = (which ? 196608 : 0) + l * 65536 + sw_byte(n, k);
        ws[dst] = f2fp8(W[l * 65536 + k * 256 + n]);
    } else if (idx < 409600) {
        int j = idx - 393216;                      // [0, 16384)
        int which = j >= 8192;
        int e = j & 8191;
        int n = e >> 5, k = e & 31;
        int ink = which ? 7 : 6;
        const float* W = which ? dWin : sWin;
        float v = (k < ink) ? W[k * 256 + n] : 0.f;
        ((short*)(ws + 393216))[j] = (short)f2bf(v);
    } else {
        int j = idx - 409600;                      // [0, 8192)
        int which = j >= 4096;
        int e = j & 4095;
        int o = e >> 8, k = e & 255;
        int outd = which ? 5 : 4;
        const float* W = which ? dWout : sWout;
        float v = (o < outd) ? W[k * outd + o] : 0.f;
        ws[425984 + j] = f2fp8(v);
    }
}

extern "C" void kernel_launch(void* const* d_in, const int* in_sizes, int n_in,
                              void* d_out, int out_size, void* d_ws, size_t ws_size,
                              hipStream_t stream)
{
    const float* points = (const float*)d_in[0];
    const float* dirs   = (const float*)d_in[1];
    const float* z_vals = (const float*)d_in[2];
    const float* timev  = (const float*)d_in[3];
    const float* sWin   = (const float*)d_in[4];
    const float* sbin   = (const float*)d_in[5];
    const float* sWh    = (const float*)d_in[6];
    const float* sbh    = (const float*)d_in[7];
    const float* sWout  = (const float*)d_in[8];
    const float* sbout  = (const float*)d_in[9];
    const float* dWin   = (const float*)d_in[10];
    const float* dbin   = (const float*)d_in[11];
    const float* dWh    = (const float*)d_in[12];
    const float* dbh    = (const float*)d_in[13];
    const float* dWout  = (const float*)d_in[14];
    const float* dbout  = (const float*)d_in[15];

    unsigned char* wsb = (unsigned char*)d_ws;

    convert_weights<<<1632, 256, 0, stream>>>(sWh, dWh, sWin, dWin, sWout, dWout, wsb);

    nerf_kernel<<<R_, 512, 0, stream>>>(
        points, dirs, z_vals, timev,
        sbin, sbh, sbout, dbin, dbh, dbout,
        wsb, (float*)d_out);
}

// Round 17
// 219.776 us; speedup vs baseline: 2.2587x; 1.4041x over previous
//
#include <hip/hip_runtime.h>

#define R_ 4096
#define S_ 64
#define H_ 256
#define N_ (R_ * S_)
#define FARD 1e10f

typedef __attribute__((ext_vector_type(4))) float f32x4;
typedef __attribute__((ext_vector_type(8))) short short8;

union U8 { short8 s; uint4 u; };

__device__ __forceinline__ unsigned int cvt_pk_bf16(float lo, float hi) {
    unsigned int r;
    asm("v_cvt_pk_bf16_f32 %0, %1, %2" : "=v"(r) : "v"(lo), "v"(hi));
    return r;
}
__device__ __forceinline__ unsigned short f2bf(float f) {
    unsigned int x = __float_as_uint(f);
    x += 0x7fffu + ((x >> 16) & 1u);          // RNE
    return (unsigned short)(x >> 16);
}
__device__ __forceinline__ unsigned int pk4_fp8(float a0, float a1, float a2, float a3) {
    unsigned int lo, hi;
    asm("v_cvt_pk_fp8_f32 %0, %1, %2" : "=v"(lo) : "v"(a0), "v"(a1));
    asm("v_cvt_pk_fp8_f32 %0, %1, %2" : "=v"(hi) : "v"(a2), "v"(a3));
    return (lo & 0xffffu) | (hi << 16);
}
__device__ __forceinline__ unsigned char f2fp8(float v) {
    unsigned int r;
    asm("v_cvt_pk_fp8_f32 %0, %1, %2" : "=v"(r) : "v"(v), "v"(0.0f));
    return (unsigned char)(r & 0xff);
}
__device__ __forceinline__ float sigmoidf_(float x) { return 1.0f / (1.0f + expf(-x)); }

// Swizzled byte offset in a [row][256] fp8 panel (R16-verified: conflicts 9x down)
__device__ __forceinline__ int sw_byte(int row, int col) {
    return (row << 8) + (col ^ ((row & 15) << 3));
}

typedef const __attribute__((address_space(1))) unsigned char* gas1;
typedef __attribute__((address_space(3))) unsigned char* las3;
// async DMA 64KB global->LDS; swizzle pre-baked in global layout (m173).
__device__ __forceinline__ void stage64k(const unsigned char* g, unsigned char* l, int tid) {
#pragma unroll
    for (int i = 0; i < 8; ++i)
        __builtin_amdgcn_global_load_lds((gas1)(g + i * 8192 + tid * 16),
                                         (las3)(l + i * 8192 + tid * 16), 16, 0, 0);
}

// ---- hidden layer, single shared wbuf: compute -> barrier (wbuf+act reads done)
// -> issue next-layer DMA into wbuf + store act -> barrier (vmcnt drained =>
// wbuf ready, act visible). Cross-block TLP (2 blocks/CU) covers the DMA window.
__device__ void hidden_layer(unsigned char* act, unsigned char* wbuf,
                             const unsigned char* __restrict__ next_panel,
                             const float* __restrict__ bias, int lane, int wv, int tid)
{
    const int m0 = lane & 15;
    const int q  = lane >> 4;
    const int nw = wv << 5;            // 32 neurons per wave

    f32x4 acc[2][4];                   // 32 AGPR
#pragma unroll
    for (int nt = 0; nt < 2; ++nt) {
        const float4 bv = *(const float4*)&bias[nw + nt * 16 + 4 * q];
#pragma unroll
        for (int mt = 0; mt < 4; ++mt) {
            acc[nt][mt][0] = bv.x; acc[nt][mt][1] = bv.y;
            acc[nt][mt][2] = bv.z; acc[nt][mt][3] = bv.w;
        }
    }

    __builtin_amdgcn_s_setprio(1);
#pragma unroll
    for (int kc = 0; kc < 8; ++kc) {               // K = 8 chunks of 32
        const int kb = kc * 32 + 8 * q;
        long long B[4];
#pragma unroll
        for (int mt = 0; mt < 4; ++mt)
            B[mt] = *(const long long*)(act + sw_byte(mt * 16 + m0, kb));
#pragma unroll
        for (int nt = 0; nt < 2; ++nt) {
            long long A = *(const long long*)(wbuf + sw_byte(nw + nt * 16 + m0, kb));
#pragma unroll
            for (int mt = 0; mt < 4; ++mt)
                acc[nt][mt] = __builtin_amdgcn_mfma_f32_16x16x32_fp8_fp8(
                    A, B[mt], acc[nt][mt], 0, 0, 0);
        }
    }
    __builtin_amdgcn_s_setprio(0);
    __syncthreads();                   // wbuf + act reads complete
    if (next_panel) stage64k(next_panel, wbuf, tid);   // async, drains at next barrier
#pragma unroll
    for (int nt = 0; nt < 2; ++nt)
#pragma unroll
        for (int mt = 0; mt < 4; ++mt) {
            f32x4 a = acc[nt][mt];
            unsigned int u = pk4_fp8(fmaxf(a[0], 0.f), fmaxf(a[1], 0.f),
                                     fmaxf(a[2], 0.f), fmaxf(a[3], 0.f));
            *(unsigned int*)(act + sw_byte(mt * 16 + m0, nw + nt * 16 + 4 * q)) = u;
        }
    __syncthreads();                   // act visible; DMA drained
}

// ---- input layer: bf16 MFMA, fp8 swizzled act output (stores only; caller syncs)
__device__ void input_mfma(const float* __restrict__ pts, const float* __restrict__ drs,
                           const float* __restrict__ tv,
                           const short* __restrict__ WinT, const float* __restrict__ bin,
                           unsigned char* act, int base, int lane, int wv)
{
    const int m0 = lane & 15;
    const int q  = lane >> 4;
    const int nw = wv << 5;

    short8 B[4];
#pragma unroll
    for (int mt = 0; mt < 4; ++mt) {
        U8 ub;
        if (q == 0) {
            const int s = base + mt * 16 + m0;
            float p0 = pts[s * 3 + 0], p1 = pts[s * 3 + 1], p2 = pts[s * 3 + 2];
            float e0 = drs[s * 3 + 0], e1 = drs[s * 3 + 1], e2 = drs[s * 3 + 2];
            float t  = tv[s];
            ub.u = make_uint4(cvt_pk_bf16(p0, p1), cvt_pk_bf16(p2, e0),
                              cvt_pk_bf16(e1, e2), cvt_pk_bf16(t, 0.f));
        } else {
            ub.u = make_uint4(0, 0, 0, 0);
        }
        B[mt] = ub.s;
    }

    f32x4 acc[2][4];
#pragma unroll
    for (int nt = 0; nt < 2; ++nt) {
        const float4 bv = *(const float4*)&bin[nw + nt * 16 + 4 * q];
#pragma unroll
        for (int mt = 0; mt < 4; ++mt) {
            acc[nt][mt][0] = bv.x; acc[nt][mt][1] = bv.y;
            acc[nt][mt][2] = bv.z; acc[nt][mt][3] = bv.w;
        }
    }
#pragma unroll
    for (int nt = 0; nt < 2; ++nt) {
        // rows k>=INK of WinT are zero, so q!=0 slices contribute 0
        short8 A = *(const short8*)&WinT[(nw + nt * 16 + m0) * 32 + 8 * q];
#pragma unroll
        for (int mt = 0; mt < 4; ++mt)
            acc[nt][mt] = __builtin_amdgcn_mfma_f32_16x16x32_bf16(A, B[mt], acc[nt][mt], 0, 0, 0);
    }
#pragma unroll
    for (int nt = 0; nt < 2; ++nt)
#pragma unroll
        for (int mt = 0; mt < 4; ++mt) {
            f32x4 a = acc[nt][mt];
            unsigned int u = pk4_fp8(fmaxf(a[0], 0.f), fmaxf(a[1], 0.f),
                                     fmaxf(a[2], 0.f), fmaxf(a[3], 0.f));
            *(unsigned int*)(act + sw_byte(mt * 16 + m0, nw + nt * 16 + 4 * q)) = u;
        }
}

// ---- output layer fp8 -> REGISTERS (o[0..3] on q==0; o4 slot on q==1)
template <int OUTD>
__device__ void out_mfma(const unsigned char* act, const unsigned char* __restrict__ WoT,
                         const float* __restrict__ bout, float* o, int lane, int wv)
{
    const int m0 = lane & 15;
    const int q  = lane >> 4;
    const int m  = (wv << 4) + m0;

    f32x4 acc = {0.f, 0.f, 0.f, 0.f};
#pragma unroll
    for (int ks = 0; ks < 8; ++ks) {
        long long A = *(const long long*)(WoT + m0 * H_ + ks * 32 + 8 * q);
        long long B = *(const long long*)(act + sw_byte(m, ks * 32 + 8 * q));
        acc = __builtin_amdgcn_mfma_f32_16x16x32_fp8_fp8(A, B, acc, 0, 0, 0);
    }
    if (q == 0) {
        o[0] = acc[0] + bout[0]; o[1] = acc[1] + bout[1];
        o[2] = acc[2] + bout[2]; o[3] = acc[3] + bout[3];
    }
    if (OUTD == 5 && q == 1) o[4] = acc[0] + bout[4];
}

// 512 threads = 8 waves x 32 neurons. LDS: 64K wbuf + 16K act = 80KB exactly
// -> 2 blocks/CU = 4 waves/SIMD. Out-layer results ride in registers.
__global__ __launch_bounds__(512, 4) void nerf_kernel(
    const float* __restrict__ points, const float* __restrict__ dirs,
    const float* __restrict__ z_vals, const float* __restrict__ timev,
    const float* __restrict__ sbin, const float* __restrict__ sbh, const float* __restrict__ sbout,
    const float* __restrict__ dbin, const float* __restrict__ dbh, const float* __restrict__ dbout,
    const unsigned char* __restrict__ wsb,
    float* __restrict__ out)
{
    __shared__ __align__(16) unsigned char wbuf[65536];
    __shared__ __align__(16) unsigned char act[64 * H_];   // 16KB, in-place

    const int tid  = threadIdx.x;
    const int lane = tid & 63;
    const int wv   = tid >> 6;
    const int ray  = blockIdx.x;
    const int base = ray * 64;

    const unsigned char* sW8   = wsb;                    // 3*65536 fp8, pre-swizzled
    const unsigned char* dW8   = wsb + 196608;
    const short* sWinT = (const short*)(wsb + 393216);   // 256*32 bf16
    const short* dWinT = (const short*)(wsb + 409600);
    const unsigned char* sWoT8 = wsb + 425984;           // 16*256 fp8
    const unsigned char* dWoT8 = wsb + 430080;

    // ---- static MLP ----
    stage64k(sW8 + 0 * 65536, wbuf, tid);                // s_h0 (overlaps input)
    input_mfma(points, dirs, timev, sWinT, sbin, act, base, lane, wv);
    __syncthreads();                                     // act ready; s_h0 staged

    hidden_layer(act, wbuf, sW8 + 1 * 65536, sbh + 0 * H_, lane, wv, tid);
    hidden_layer(act, wbuf, sW8 + 2 * 65536, sbh + 1 * H_, lane, wv, tid);
    hidden_layer(act, wbuf, dW8 + 0 * 65536, sbh + 2 * H_, lane, wv, tid);

    float so[4];
    if (wv < 4) out_mfma<4>(act, sWoT8, sbout, so, lane, wv);
    __syncthreads();                                     // act reads done (d_h0 staged)

    // ---- dynamic MLP ----
    input_mfma(points, dirs, timev, dWinT, dbin, act, base, lane, wv);
    __syncthreads();                                     // act ready

    hidden_layer(act, wbuf, dW8 + 1 * 65536, dbh + 0 * H_, lane, wv, tid);
    hidden_layer(act, wbuf, dW8 + 2 * 65536, dbh + 1 * H_, lane, wv, tid);
    hidden_layer(act, wbuf, nullptr,         dbh + 2 * H_, lane, wv, tid);

    float dox[5];
    if (wv < 4) out_mfma<5>(act, dWoT8, dbout, dox, lane, wv);
    __syncthreads();                                     // act reads done; act now dead

    // ---- stash so/do into dead act (float layout [64][9]) ----
    float* mixb = (float*)act;
    if (wv < 4) {
        const int m0 = lane & 15;
        const int q  = lane >> 4;
        const int m  = (wv << 4) + m0;
        if (q == 0) {
            mixb[m * 9 + 0] = so[0];  mixb[m * 9 + 1] = so[1];
            mixb[m * 9 + 2] = so[2];  mixb[m * 9 + 3] = so[3];
            mixb[m * 9 + 4] = dox[0]; mixb[m * 9 + 5] = dox[1];
            mixb[m * 9 + 6] = dox[2]; mixb[m * 9 + 7] = dox[3];
        }
        if (q == 1) mixb[m * 9 + 8] = dox[4];
    }
    __syncthreads();

    // ---- mix + fused render: wave 0, lane s = sample
    if (tid < 64) {
        const int s = tid;
        float so0 = mixb[s * 9 + 0], so1 = mixb[s * 9 + 1];
        float so2 = mixb[s * 9 + 2], so3 = mixb[s * 9 + 3];
        float d0 = mixb[s * 9 + 4], d1 = mixb[s * 9 + 5], d2 = mixb[s * 9 + 6];
        float d3 = mixb[s * 9 + 7], d4 = mixb[s * 9 + 8];

        float bw  = sigmoidf_(d4);
        float omb = 1.f - bw;
        float sigma = omb * so0 + bw * d0;
        float cr = omb * sigmoidf_(so1) + bw * sigmoidf_(d1);
        float cg = omb * sigmoidf_(so2) + bw * sigmoidf_(d2);
        float cb = omb * sigmoidf_(so3) + bw * sigmoidf_(d3);

        float z  = z_vals[base + s];
        float zn = __shfl_down(z, 1);
        float delta = (s < 63) ? (zn - z) : FARD;
        float ex    = fminf(-sigma * delta, 60.0f);   // finite where ref overflows
        float alpha = 1.f - expf(ex);
        float f     = 1.f - alpha + 1e-10f;
        float p = f;
#pragma unroll
        for (int d = 1; d < 64; d <<= 1) {
            float pu = __shfl_up(p, d);
            if (s >= d) p *= pu;
        }
        float T = (s == 0) ? 1.f : __shfl_up(p, 1);
        float w = alpha * T;

        float* rgb_map   = out;
        float* depth_map = out + R_ * 3;
        float* weights   = out + R_ * 4;
        float* swei      = weights + N_;
        float* dwei      = swei + N_;
        weights[base + s] = w;
        swei[base + s]    = omb * w;
        dwei[base + s]    = bw * w;

        float c0 = w * cr, c1 = w * cg, c2 = w * cb, dd = w * z;
#pragma unroll
        for (int d = 32; d >= 1; d >>= 1) {
            c0 += __shfl_down(c0, d);
            c1 += __shfl_down(c1, d);
            c2 += __shfl_down(c2, d);
            dd += __shfl_down(dd, d);
        }
        if (s == 0) {
            rgb_map[ray * 3 + 0] = c0;
            rgb_map[ray * 3 + 1] = c1;
            rgb_map[ray * 3 + 2] = c2;
            depth_map[ray] = dd;
        }
    }
}

// ---- prep. Layout (bytes):
// [0)        sW8    3*65536 fp8  PRE-SWIZZLED [l][n][k^((n&15)<<3)] = W[l][k][n]
// [196608)   dW8    3*65536 fp8  same
// [393216)   sWinT  256*32 bf16 (k>=6 zero-padded)
// [409600)   dWinT  256*32 bf16 (k>=7 zero-padded)
// [425984)   sWoT8  16*256 fp8  (o>=4 zero-padded)
// [430080)   dWoT8  16*256 fp8  (o>=5 zero-padded)
__global__ void convert_weights(const float* __restrict__ sWh, const float* __restrict__ dWh,
                                const float* __restrict__ sWin, const float* __restrict__ dWin,
                                const float* __restrict__ sWout, const float* __restrict__ dWout,
                                unsigned char* __restrict__ ws)
{
    int idx = blockIdx.x * 256 + threadIdx.x;      // 417792 total
    if (idx < 393216) {
        int which = idx >= 196608;
        int rem   = which ? idx - 196608 : idx;
        int l = rem >> 16, e = rem & 65535, k = e >> 8, n = e & 255;
        const float* W = which ? dWh : sWh;
        int dst = (which ? 196608 : 0) + l * 65536 + sw_byte(n, k);
        ws[dst] = f2fp8(W[l * 65536 + k * 256 + n]);
    } else if (idx < 409600) {
        int j = idx - 393216;                      // [0, 16384)
        int which = j >= 8192;
        int e = j & 8191;
        int n = e >> 5, k = e & 31;
        int ink = which ? 7 : 6;
        const float* W = which ? dWin : sWin;
        float v = (k < ink) ? W[k * 256 + n] : 0.f;
        ((short*)(ws + 393216))[j] = (short)f2bf(v);
    } else {
        int j = idx - 409600;                      // [0, 8192)
        int which = j >= 4096;
        int e = j & 4095;
        int o = e >> 8, k = e & 255;
        int outd = which ? 5 : 4;
        const float* W = which ? dWout : sWout;
        float v = (o < outd) ? W[k * outd + o] : 0.f;
        ws[425984 + j] = f2fp8(v);
    }
}

extern "C" void kernel_launch(void* const* d_in, const int* in_sizes, int n_in,
                              void* d_out, int out_size, void* d_ws, size_t ws_size,
                              hipStream_t stream)
{
    const float* points = (const float*)d_in[0];
    const float* dirs   = (const float*)d_in[1];
    const float* z_vals = (const float*)d_in[2];
    const float* timev  = (const float*)d_in[3];
    const float* sWin   = (const float*)d_in[4];
    const float* sbin   = (const float*)d_in[5];
    const float* sWh    = (const float*)d_in[6];
    const float* sbh    = (const float*)d_in[7];
    const float* sWout  = (const float*)d_in[8];
    const float* sbout  = (const float*)d_in[9];
    const float* dWin   = (const float*)d_in[10];
    const float* dbin   = (const float*)d_in[11];
    const float* dWh    = (const float*)d_in[12];
    const float* dbh    = (const float*)d_in[13];
    const float* dWout  = (const float*)d_in[14];
    const float* dbout  = (const float*)d_in[15];

    unsigned char* wsb = (unsigned char*)d_ws;

    convert_weights<<<1632, 256, 0, stream>>>(sWh, dWh, sWin, dWin, sWout, dWout, wsb);

    nerf_kernel<<<R_, 512, 0, stream>>>(
        points, dirs, z_vals, timev,
        sbin, sbh, sbout, dbin, dbh, dbout,
        wsb, (float*)d_out);
}